// Round 7
// baseline (3106.221 us; speedup 1.0000x reference)
//
#include <hip/hip_runtime.h>
#include <stdint.h>
#include <stddef.h>

// ---------------------------------------------------------------------------
// Discriminator: embedding [64,512] -> GRU(512->1024, 512 steps) -> FC(1024->2)
//   k1 embed_k : gather emb rows -> X fp16 [S*B, 512]   (row = s*64+b)
//   k2 wconv   : w_ih fp32 -> fp16
//   k3 gemm_gx : GXp = X @ w_ih^T + b_ih -> fp16, BLOCKED layout:
//                GXp[(s*64+ug)*4+bg][gate][b][u]  (768 f16 per block)
//   k4 gru_rec : persistent 256-WG kernel, 4 bg x 64 ug. w_hh MFMA B-frags
//                LOOP-INVARIANT IN VGPRS (96/wave) -- no per-step LDS reads.
//                R6-proven sync: ack'd sc0sc1 h stores -> relaxed counter;
//                consumers poll counter -> ONE bulk load. gx prefetched one
//                step ahead; store ack via counted vmcnt(3) + raw s_barrier.
//   k5 fc_k    : logits = h_last @ fc_w^T + fc_b -> d_out fp32 [64,2]
// ---------------------------------------------------------------------------

typedef _Float16 f16;
typedef _Float16 f16x4 __attribute__((ext_vector_type(4)));
typedef _Float16 f16x8 __attribute__((ext_vector_type(8)));
typedef float f32x4 __attribute__((ext_vector_type(4)));
typedef unsigned int u32;

#define NB 64      // batch
#define NS 512     // seq len
#define NE 512     // embedding dim
#define NH 1024    // hidden
#define G3 3072    // 3*NH

struct Gx3 { f16 r, z, n; };

// ---------------------------------------------------------------- embedding
__global__ __launch_bounds__(256) void embed_k(const int* __restrict__ seq,
                                               const float* __restrict__ emb,
                                               f16* __restrict__ X) {
  int rr = blockIdx.x * 4 + (threadIdx.x >> 6);   // row = s*64 + b
  int lane = threadIdx.x & 63;
  int s = rr >> 6, b = rr & 63;
  int idx = seq[b * NS + s];
  const float* src = emb + (size_t)idx * NE + lane * 8;
  float4 v0 = *(const float4*)(src);
  float4 v1 = *(const float4*)(src + 4);
  f16x8 o;
  o[0] = (f16)v0.x; o[1] = (f16)v0.y; o[2] = (f16)v0.z; o[3] = (f16)v0.w;
  o[4] = (f16)v1.x; o[5] = (f16)v1.y; o[6] = (f16)v1.z; o[7] = (f16)v1.w;
  *(f16x8*)(&X[(size_t)rr * NE + lane * 8]) = o;
}

// ---------------------------------------------------------------- w_ih -> fp16
__global__ __launch_bounds__(256) void wconv(const float* __restrict__ w,
                                             f16* __restrict__ o) {
  int i = (blockIdx.x * 256 + threadIdx.x) * 4;
  float4 v = *(const float4*)(&w[i]);
  f16x4 t = {(f16)v.x, (f16)v.y, (f16)v.z, (f16)v.w};
  *(f16x4*)(&o[i]) = t;
}

// ---------------------------------------------------------------- gx GEMM
// C[m,g] = sum_k X[m,k]*W[g,k] + bih[g]; M=32768 N=3072 K=512.
// Output written in GRU-blocked layout:
//   addr = (s*256 + ug*4 + bg)*768 + gate*256 + b*16 + u
//   where m = s*64 + bg*16 + b,  g = gate*1024 + ug*16 + u.
__global__ __launch_bounds__(256) void gemm_gx(const f16* __restrict__ X,
                                               const f16* __restrict__ W,
                                               const float* __restrict__ bih,
                                               f16* __restrict__ GXp) {
  __shared__ f16 As[128][40];   // +8 pad: frag-read 2-way banks only
  __shared__ f16 Bs[128][40];
  int tm = blockIdx.x & 255, tn = blockIdx.x >> 8;   // 256 x 24
  int m0 = tm * 128, n0 = tn * 128;
  int tid = threadIdx.x, lane = tid & 63, w = tid >> 6;
  int wm = w & 1, wn = w >> 1;
  f32x4 acc[4][4] = {};
  for (int k0 = 0; k0 < 512; k0 += 32) {
    __syncthreads();
    #pragma unroll
    for (int i = 0; i < 2; i++) {
      int c = tid + i * 256;          // 512 chunks of 16B per operand
      int r = c >> 2, seg = c & 3;
      *(f16x8*)(&As[r][seg * 8]) = *(const f16x8*)(&X[(size_t)(m0 + r) * 512 + k0 + seg * 8]);
      *(f16x8*)(&Bs[r][seg * 8]) = *(const f16x8*)(&W[(size_t)(n0 + r) * 512 + k0 + seg * 8]);
    }
    __syncthreads();
    f16x8 af[4], bf[4];
    int rA = lane & 15, kA = (lane >> 4) * 8;
    #pragma unroll
    for (int i = 0; i < 4; i++) af[i] = *(const f16x8*)(&As[wm * 64 + i * 16 + rA][kA]);
    #pragma unroll
    for (int j = 0; j < 4; j++) bf[j] = *(const f16x8*)(&Bs[wn * 64 + j * 16 + rA][kA]);
    #pragma unroll
    for (int i = 0; i < 4; i++)
      #pragma unroll
      for (int j = 0; j < 4; j++)
        acc[i][j] = __builtin_amdgcn_mfma_f32_16x16x32_f16(af[i], bf[j], acc[i][j], 0, 0, 0);
  }
  int col = lane & 15, rq = lane >> 4;
  #pragma unroll
  for (int j = 0; j < 4; j++) {
    int g = n0 + wn * 64 + j * 16 + col;
    float bias = bih[g];
    int gate = g >> 10, ugu = g & 1023;
    int gob = gate * 256 + (ugu & 15);      // + b*16 added per element
    int ug4 = (ugu >> 4) * 4;
    #pragma unroll
    for (int i = 0; i < 4; i++) {
      int mbase = m0 + wm * 64 + i * 16 + rq * 4;
      #pragma unroll
      for (int q = 0; q < 4; q++) {
        int m = mbase + q;
        int s = m >> 6, bglob = m & 63;
        size_t addr = (size_t)(s * 256 + ug4 + (bglob >> 4)) * 768 + gob + (bglob & 15) * 16;
        GXp[addr] = (f16)(acc[i][j][q] + bias);
      }
    }
  }
}

// ---------------------------------------------------------------- GRU recurrence
// HB: f16 [2][64][1024], buffer p holds h^(s) for s == p (mod 2).
// CNT[bg]: relaxed agent counter; 64*(s+1) <=> all 64 WGs of bg completed step
// s AND their h stores are complete at the coherence point (counted-vmcnt ack
// BEFORE the bump; vmcnt retires in issue order [m135], so vmcnt(3) with the 3
// younger gx-prefetch loads outstanding still guarantees the older store done).
// End-of-step barrier is a RAW s_barrier (no full vmcnt(0) drain -> the gx
// prefetch stays in flight across it). red[] WAR-safe: all LDS reads are
// consumed (lgkm-waited) before the barrier; next-step writes issue after it.
#define GRU_BODY(S, PAR, GCUR, GNXT)                                           \
  {                                                                            \
    const u32 target = 64u * (u32)(S);                                         \
    for (;;) {                                                                 \
      u32 cv_;                                                                 \
      asm volatile("global_load_dword %0, %1, off sc0 sc1\n\t"                 \
                   "s_waitcnt vmcnt(0)"                                        \
                   : "=v"(cv_) : "v"(myc) : "memory");                         \
      if (__all(cv_ >= target)) break;                                         \
      __builtin_amdgcn_s_sleep(1);                                             \
    }                                                                          \
    f16x8 af[8];                                                               \
    {                                                                          \
      const f16* hrow = HB + (size_t)(PAR) * (NB * NH)                         \
                        + ((size_t)(brow0 + r) << 10) + wv * 256 + q * 8;      \
      asm volatile(                                                            \
        "global_load_dwordx4 %0, %[p], off sc0 sc1\n\t"                        \
        "global_load_dwordx4 %1, %[p], off offset:64 sc0 sc1\n\t"              \
        "global_load_dwordx4 %2, %[p], off offset:128 sc0 sc1\n\t"             \
        "global_load_dwordx4 %3, %[p], off offset:192 sc0 sc1\n\t"             \
        "global_load_dwordx4 %4, %[p], off offset:256 sc0 sc1\n\t"             \
        "global_load_dwordx4 %5, %[p], off offset:320 sc0 sc1\n\t"             \
        "global_load_dwordx4 %6, %[p], off offset:384 sc0 sc1\n\t"             \
        "global_load_dwordx4 %7, %[p], off offset:448 sc0 sc1\n\t"             \
        "s_waitcnt vmcnt(0)"                                                   \
        : "=&v"(af[0]), "=&v"(af[1]), "=&v"(af[2]), "=&v"(af[3]),              \
          "=&v"(af[4]), "=&v"(af[5]), "=&v"(af[6]), "=&v"(af[7])               \
        : [p] "v"(hrow)                                                        \
        : "memory");                                                           \
      __builtin_amdgcn_sched_barrier(0);                                       \
    }                                                                          \
    f32x4 ac0 = {}, ac1 = {}, ac2 = {};                                        \
    _Pragma("unroll")                                                          \
    for (int kk = 0; kk < 8; kk++) {                                           \
      ac0 = __builtin_amdgcn_mfma_f32_16x16x32_f16(af[kk], bfr[0][kk], ac0, 0, 0, 0); \
      ac1 = __builtin_amdgcn_mfma_f32_16x16x32_f16(af[kk], bfr[1][kk], ac1, 0, 0, 0); \
      ac2 = __builtin_amdgcn_mfma_f32_16x16x32_f16(af[kk], bfr[2][kk], ac2, 0, 0, 0); \
    }                                                                          \
    _Pragma("unroll")                                                          \
    for (int q2 = 0; q2 < 4; q2++) {                                           \
      red[wv][0][q * 4 + q2][r] = ac0[q2];                                     \
      red[wv][1][q * 4 + q2][r] = ac1[q2];                                     \
      red[wv][2][q * 4 + q2][r] = ac2[q2];                                     \
    }                                                                          \
    __syncthreads();                                                           \
    float ghr = bh_r, ghz = bh_z, ghn = bh_n;                                  \
    _Pragma("unroll")                                                          \
    for (int w2 = 0; w2 < 4; w2++) {                                           \
      ghr += red[w2][0][b][u];                                                 \
      ghz += red[w2][1][b][u];                                                 \
      ghn += red[w2][2][b][u];                                                 \
    }                                                                          \
    const float xr = (float)GCUR.r, xz = (float)GCUR.z, xn = (float)GCUR.n;    \
    const float rg = 1.f / (1.f + __expf(-(xr + ghr)));                        \
    const float zz = 1.f / (1.f + __expf(-(xz + ghz)));                        \
    float nv;                                                                  \
    {                                                                          \
      const float a_ = xn + rg * ghn;                                          \
      const float tt = __expf(-2.f * fabsf(a_));                               \
      nv = (1.f - tt) / (1.f + tt);                                            \
      nv = a_ < 0.f ? -nv : nv;                                                \
    }                                                                          \
    hown = (1.f - zz) * nv + zz * hown;                                        \
    {                                                                          \
      f16* hdst = HB + (size_t)(1 - (PAR)) * (NB * NH)                         \
                  + ((size_t)(brow0 + b) << 10) + ugl;                         \
      union { f16 h; unsigned short us_; } cv2;                                \
      cv2.h = (f16)hown;                                                       \
      u32 hv = (u32)cv2.us_;                                                   \
      asm volatile("global_store_short %0, %1, off sc0 sc1"                    \
                   :: "v"(hdst), "v"(hv) : "memory");                          \
    }                                                                          \
    if ((S) == NS - 1) hlast[((size_t)(brow0 + b) << 10) + ugl] = hown;        \
    {                                                                          \
      const int sn_ = ((S) + 1 < NS) ? (S) + 1 : (S);                          \
      const f16* gxn = GXp + (size_t)(sn_ * 256 + ug * 4 + bg) * 768 + tid;    \
      GNXT.r = gxn[0];                                                         \
      GNXT.z = gxn[256];                                                       \
      GNXT.n = gxn[512];                                                       \
    }                                                                          \
    asm volatile("s_waitcnt vmcnt(3) lgkmcnt(0)" ::: "memory");                \
    __builtin_amdgcn_s_barrier();                                              \
    if (tid == 0)                                                              \
      __hip_atomic_fetch_add((u32*)myc, 1u, __ATOMIC_RELAXED,                  \
                             __HIP_MEMORY_SCOPE_AGENT);                        \
  }

__global__ __launch_bounds__(256, 1) void gru_rec(const float* __restrict__ whh,
                                                  const float* __restrict__ bhh,
                                                  const f16* __restrict__ GXp,
                                                  f16* __restrict__ HB,       // [2][64][1024]
                                                  u32* __restrict__ CNT,      // [4*32]
                                                  float* __restrict__ hlast) { // [64][1024]
  __shared__ float red[4][3][16][17];   // pad 17 -> conflict-free reduce
  const int tid = threadIdx.x, lane = tid & 63, wv = tid >> 6;
  const int bg = blockIdx.x >> 6, ug = blockIdx.x & 63;
  const int brow0 = bg * 16;
  const int q = lane >> 4, r = lane & 15;

  // ---- loop-invariant w_hh B-fragments -> VGPRs (96 regs/wave).
  // lane (q,r) elem j of bfr[n][kk] = W[n*1024+ug*16+r][wv*256+kk*32+q*8+j]
  f16x8 bfr[3][8];
  #pragma unroll
  for (int n = 0; n < 3; n++)
    #pragma unroll
    for (int kk = 0; kk < 8; kk++) {
      const float* p = whh + (size_t)(n * NH + ug * 16 + r) * NH + wv * 256 + kk * 32 + q * 8;
      float4 v0 = *(const float4*)p;
      float4 v1 = *(const float4*)(p + 4);
      f16x8 t;
      t[0] = (f16)v0.x; t[1] = (f16)v0.y; t[2] = (f16)v0.z; t[3] = (f16)v0.w;
      t[4] = (f16)v1.x; t[5] = (f16)v1.y; t[6] = (f16)v1.z; t[7] = (f16)v1.w;
      bfr[n][kk] = t;
    }

  const int b = tid >> 4, u = tid & 15;
  const int ugl = ug * 16 + u;
  const float bh_r = bhh[ugl], bh_z = bhh[NH + ugl], bh_n = bhh[2 * NH + ugl];
  float hown = 0.f;
  const u32* myc = CNT + bg * 32;       // 128B-separated per-bg counters

  // preload gx for s=0 (coalesced blocked layout: 3 x 128B per wave)
  Gx3 ga, gb;
  {
    const f16* gx0 = GXp + (size_t)(ug * 4 + bg) * 768 + tid;
    ga.r = gx0[0]; ga.z = gx0[256]; ga.n = gx0[512];
  }

  #pragma unroll 1
  for (int s = 0; s < NS; s += 2) {
    GRU_BODY(s, 0, ga, gb)
    GRU_BODY(s + 1, 1, gb, ga)
  }
}

// ---------------------------------------------------------------- FC head
__global__ __launch_bounds__(64) void fc_k(const float* __restrict__ hl,
                                           const float* __restrict__ fw,
                                           const float* __restrict__ fb,
                                           float* __restrict__ out) {
  int b = blockIdx.x, t = threadIdx.x;
  float a0 = 0.f, a1 = 0.f;
  for (int k = t; k < NH; k += 64) {
    float h = hl[b * NH + k];
    a0 += h * fw[k];
    a1 += h * fw[NH + k];
  }
  #pragma unroll
  for (int off = 32; off; off >>= 1) {
    a0 += __shfl_down(a0, off);
    a1 += __shfl_down(a1, off);
  }
  if (t == 0) {
    out[b * 2 + 0] = a0 + fb[0];
    out[b * 2 + 1] = a1 + fb[1];
  }
}

// ---------------------------------------------------------------- launcher
extern "C" void kernel_launch(void* const* d_in, const int* in_sizes, int n_in,
                              void* d_out, int out_size, void* d_ws, size_t ws_size,
                              hipStream_t stream) {
  const int*   seq = (const int*)d_in[0];
  const float* emb = (const float*)d_in[1];
  const float* wih = (const float*)d_in[2];
  const float* whh = (const float*)d_in[3];
  const float* bih = (const float*)d_in[4];
  const float* bhh = (const float*)d_in[5];
  const float* fcw = (const float*)d_in[6];
  const float* fcb = (const float*)d_in[7];
  float* out = (float*)d_out;

  char* ws = (char*)d_ws;
  size_t off = 0;
  f16* X = (f16*)(ws + off);   off += (size_t)NS * NB * NE * 2;   // 33.6 MB
  f16* W16 = (f16*)(ws + off); off += (size_t)G3 * NE * 2;        // 3.1 MB
  f16* GXp = (f16*)(ws + off); off += (size_t)NS * NB * G3 * 2;   // 201 MB
  f16* HB = (f16*)(ws + off);  off += (size_t)2 * NB * NH * 2;    // 256 KB
  u32* CNT = (u32*)(ws + off); off += 4 * 32 * 4;                 // 512 B
  float* HL = (float*)(ws + off); off += (size_t)NB * NH * 4;     // 256 KB
  if (ws_size < off) return;  // insufficient workspace -> fail visibly, no OOB

  // Zero h0 (parity-0 buffer) and counters every call (ws is 0xAA-poisoned).
  hipMemsetAsync(HB, 0, (size_t)2 * NB * NH * 2 + 4 * 32 * 4, stream);

  embed_k<<<(NS * NB) / 4, 256, 0, stream>>>(seq, emb, X);
  wconv<<<(G3 * NE) / 1024, 256, 0, stream>>>(wih, W16);
  gemm_gx<<<256 * 24, 256, 0, stream>>>(X, W16, bih, GXp);
  gru_rec<<<256, 256, 0, stream>>>(whh, bhh, GXp, HB, CNT, HL);
  fc_k<<<NB, 64, 0, stream>>>(HL, fcw, fcb, out);
}

// Round 8
// 2075.649 us; speedup vs baseline: 1.4965x; 1.4965x over previous
//
#include <hip/hip_runtime.h>
#include <stdint.h>
#include <stddef.h>

// ---------------------------------------------------------------------------
// Discriminator: embedding [64,512] -> GRU(512->1024, 512 steps) -> FC(1024->2)
//   k1 embed_k : gather emb rows -> X fp16 [S*B, 512]   (row = s*64+b)
//   k2 wconv   : w_ih fp32 -> fp16
//   k3 gemm_gx : GX = X @ w_ih^T + b_ih  -> fp16 [S*B, 3072]  (MFMA 128x128 tile)
//   k4 gru_rec : persistent 256-WG kernel, 4 batch-groups x 64 unit-groups,
//                w_hh slice LDS-resident fp16 (R6 base). Sync change ONLY:
//                per-producer 128B-strided FLAG array replaces the single
//                atomic counter (kills 64-way same-address RMW serialization).
//                Producer: h store -> vmcnt(0) ack -> __syncthreads -> flag.
//   k5 fc_k    : logits = h_last @ fc_w^T + fc_b -> d_out fp32 [64,2]
// ---------------------------------------------------------------------------

typedef _Float16 f16;
typedef _Float16 f16x4 __attribute__((ext_vector_type(4)));
typedef _Float16 f16x8 __attribute__((ext_vector_type(8)));
typedef float f32x4 __attribute__((ext_vector_type(4)));
typedef unsigned int u32;

#define NB 64      // batch
#define NS 512     // seq len
#define NE 512     // embedding dim
#define NH 1024    // hidden
#define G3 3072    // 3*NH
#define FSTR 32    // flag stride in dwords (128B lines -> parallel commits)

// ---------------------------------------------------------------- embedding
__global__ __launch_bounds__(256) void embed_k(const int* __restrict__ seq,
                                               const float* __restrict__ emb,
                                               f16* __restrict__ X) {
  int rr = blockIdx.x * 4 + (threadIdx.x >> 6);   // row = s*64 + b
  int lane = threadIdx.x & 63;
  int s = rr >> 6, b = rr & 63;
  int idx = seq[b * NS + s];
  const float* src = emb + (size_t)idx * NE + lane * 8;
  float4 v0 = *(const float4*)(src);
  float4 v1 = *(const float4*)(src + 4);
  f16x8 o;
  o[0] = (f16)v0.x; o[1] = (f16)v0.y; o[2] = (f16)v0.z; o[3] = (f16)v0.w;
  o[4] = (f16)v1.x; o[5] = (f16)v1.y; o[6] = (f16)v1.z; o[7] = (f16)v1.w;
  *(f16x8*)(&X[(size_t)rr * NE + lane * 8]) = o;
}

// ---------------------------------------------------------------- w_ih -> fp16
__global__ __launch_bounds__(256) void wconv(const float* __restrict__ w,
                                             f16* __restrict__ o) {
  int i = (blockIdx.x * 256 + threadIdx.x) * 4;
  float4 v = *(const float4*)(&w[i]);
  f16x4 t = {(f16)v.x, (f16)v.y, (f16)v.z, (f16)v.w};
  *(f16x4*)(&o[i]) = t;
}

// ---------------------------------------------------------------- gx GEMM
// C[m,g] = sum_k X[m,k] * W[g,k] + bih[g];  M=32768 N=3072 K=512
__global__ __launch_bounds__(256) void gemm_gx(const f16* __restrict__ X,
                                               const f16* __restrict__ W,
                                               const float* __restrict__ bih,
                                               f16* __restrict__ GX) {
  __shared__ f16 As[128][40];   // +8 pad: frag-read 2-way banks only
  __shared__ f16 Bs[128][40];
  int tm = blockIdx.x & 255, tn = blockIdx.x >> 8;   // 256 x 24
  int m0 = tm * 128, n0 = tn * 128;
  int tid = threadIdx.x, lane = tid & 63, w = tid >> 6;
  int wm = w & 1, wn = w >> 1;
  f32x4 acc[4][4] = {};
  for (int k0 = 0; k0 < 512; k0 += 32) {
    __syncthreads();
    #pragma unroll
    for (int i = 0; i < 2; i++) {
      int c = tid + i * 256;          // 512 chunks of 16B per operand
      int r = c >> 2, seg = c & 3;
      *(f16x8*)(&As[r][seg * 8]) = *(const f16x8*)(&X[(size_t)(m0 + r) * 512 + k0 + seg * 8]);
      *(f16x8*)(&Bs[r][seg * 8]) = *(const f16x8*)(&W[(size_t)(n0 + r) * 512 + k0 + seg * 8]);
    }
    __syncthreads();
    f16x8 af[4], bf[4];
    int rA = lane & 15, kA = (lane >> 4) * 8;
    #pragma unroll
    for (int i = 0; i < 4; i++) af[i] = *(const f16x8*)(&As[wm * 64 + i * 16 + rA][kA]);
    #pragma unroll
    for (int j = 0; j < 4; j++) bf[j] = *(const f16x8*)(&Bs[wn * 64 + j * 16 + rA][kA]);
    #pragma unroll
    for (int i = 0; i < 4; i++)
      #pragma unroll
      for (int j = 0; j < 4; j++)
        acc[i][j] = __builtin_amdgcn_mfma_f32_16x16x32_f16(af[i], bf[j], acc[i][j], 0, 0, 0);
  }
  int col = lane & 15, rq = lane >> 4;
  #pragma unroll
  for (int j = 0; j < 4; j++) {
    int g = n0 + wn * 64 + j * 16 + col;
    float bias = bih[g];
    #pragma unroll
    for (int i = 0; i < 4; i++) {
      int mbase = m0 + wm * 64 + i * 16 + rq * 4;
      #pragma unroll
      for (int q = 0; q < 4; q++)
        GX[(size_t)(mbase + q) * G3 + g] = (f16)(acc[i][j][q] + bias);
    }
  }
}

// ---------------------------------------------------------------- GRU recurrence
// HB: f16 [2][64][1024], buffer p holds h^(s) for s == p (mod 2).
// FLG[bg][ug*FSTR]: flag = number of steps WG (bg,ug) completed. Stored with
// plain sc0sc1 dword (no RMW) AFTER (a) the WG's h stores are acked complete
// at the coherence point (per-thread vmcnt(0)) and (b) __syncthreads. Hence
// flag>=s+1 observed  ==>  that WG's h^(s+1) is readable. 64 flags live on 64
// separate 128B lines -> commits are parallel (vs serialized same-line RMWs).
// Consumer: each wave polls all 64 flags (one per lane) until __all(>= s),
// then ONE bulk load suffices (no tags, no retries).
// WAR safety: overwriting h^(s-1) in buffer (s+1)&1 happens only after seeing
// all flags >= s, i.e. every same-bg WG finished step s-1 INCLUDING its bulk
// read of h^(s-1).
__global__ __launch_bounds__(256, 1) void gru_rec(const float* __restrict__ whh,
                                                  const float* __restrict__ bhh,
                                                  const f16* __restrict__ GX,
                                                  f16* __restrict__ HB,       // [2][64][1024]
                                                  u32* __restrict__ FLG,      // [4][64*FSTR]
                                                  float* __restrict__ hlast) { // [64][1024]
  __shared__ f16 wl[48][1032];          // pad 8 -> 2-way bank alias only
  __shared__ float red[4][3][16][17];   // pad 17 -> conflict-free reduce
  const int tid = threadIdx.x, lane = tid & 63, wv = tid >> 6;
  const int bg = blockIdx.x >> 6, ug = blockIdx.x & 63;
  const int brow0 = bg * 16;
  const int q = lane >> 4, r = lane & 15;

  // stage w_hh slice -> LDS fp16. row lr = gate*16+c -> whh[gate*1024 + ug*16 + c]
  for (int lr = 0; lr < 48; lr++) {
    const float* srow = whh + (size_t)((lr >> 4) * NH + ug * 16 + (lr & 15)) * NH;
    float4 v = *(const float4*)(srow + tid * 4);
    f16x4 t = {(f16)v.x, (f16)v.y, (f16)v.z, (f16)v.w};
    *(f16x4*)(&wl[lr][tid * 4]) = t;
  }
  const int b = tid >> 4, u = tid & 15;
  const int ugl = ug * 16 + u;
  const float bh_r = bhh[ugl], bh_z = bhh[NH + ugl], bh_n = bhh[2 * NH + ugl];
  float hown = 0.f;
  const u32* fpoll = FLG + bg * (64 * FSTR) + lane * FSTR;  // per-lane flag
  u32* fdst = FLG + bg * (64 * FSTR) + ug * FSTR;           // own flag
  __syncthreads();

  #pragma unroll 1
  for (int s = 0; s < NS; s++) {
    // prefetch gx_t (plain cached loads; latency hides under the flag poll)
    const f16* gxp = GX + ((size_t)s * NB + brow0 + b) * G3 + ugl;
    f16 gr16 = gxp[0], gz16 = gxp[NH], gn16 = gxp[2 * NH];

    // ---- wave-autonomous flag poll: lane i watches producer i of this bg.
    // One dword load per lane per round, 64 independent 128B lines.
    {
      const u32 target = (u32)s;
      for (;;) {
        u32 fv;
        asm volatile("global_load_dword %0, %1, off sc0 sc1\n\t"
                     "s_waitcnt vmcnt(0)"
                     : "=v"(fv) : "v"(fpoll) : "memory");
        if (__all(fv >= target)) break;
        __builtin_amdgcn_s_sleep(1);
      }
    }

    // ---- single bulk load of h^(s) (fp16, lands directly as MFMA A-frags).
    // wave wv covers k in [wv*256, wv*256+256); lane (q,r): row brow0+r,
    // k = wv*256 + kk*32 + q*8 + {0..7}, kk=0..7.  8 x dwordx4 = 32KB/WG.
    f16x8 af[8];
    {
      const f16* hrow = HB + ((size_t)(s & 1) << 16)
                           + ((size_t)(brow0 + r) << 10) + wv * 256 + q * 8;
      asm volatile(
        "global_load_dwordx4 %0, %[p], off sc0 sc1\n\t"
        "global_load_dwordx4 %1, %[p], off offset:64 sc0 sc1\n\t"
        "global_load_dwordx4 %2, %[p], off offset:128 sc0 sc1\n\t"
        "global_load_dwordx4 %3, %[p], off offset:192 sc0 sc1\n\t"
        "global_load_dwordx4 %4, %[p], off offset:256 sc0 sc1\n\t"
        "global_load_dwordx4 %5, %[p], off offset:320 sc0 sc1\n\t"
        "global_load_dwordx4 %6, %[p], off offset:384 sc0 sc1\n\t"
        "global_load_dwordx4 %7, %[p], off offset:448 sc0 sc1\n\t"
        "s_waitcnt vmcnt(0)"
        : "=&v"(af[0]), "=&v"(af[1]), "=&v"(af[2]), "=&v"(af[3]),
          "=&v"(af[4]), "=&v"(af[5]), "=&v"(af[6]), "=&v"(af[7])
        : [p] "v"(hrow)
        : "memory");
      __builtin_amdgcn_sched_barrier(0);  // rule #18: keep MFMA after the waitcnt
    }
    f32x4 acc[3] = {};
    #pragma unroll
    for (int kk = 0; kk < 8; kk++) {
      const int kof = wv * 256 + kk * 32 + q * 8;
      #pragma unroll
      for (int n = 0; n < 3; n++) {
        f16x8 bfrag = *(const f16x8*)(&wl[n * 16 + r][kof]);
        acc[n] = __builtin_amdgcn_mfma_f32_16x16x32_f16(af[kk], bfrag, acc[n], 0, 0, 0);
      }
    }
    #pragma unroll
    for (int n = 0; n < 3; n++)
      #pragma unroll
      for (int q2 = 0; q2 < 4; q2++)
        red[wv][n][q * 4 + q2][r] = acc[n][q2];
    __syncthreads();                      // sync #1: red ready
    float ghr = bh_r, ghz = bh_z, ghn = bh_n;
    #pragma unroll
    for (int w2 = 0; w2 < 4; w2++) {
      ghr += red[w2][0][b][u];
      ghz += red[w2][1][b][u];
      ghn += red[w2][2][b][u];
    }
    const float xr = (float)gr16, xz = (float)gz16, xn = (float)gn16;
    const float rg = 1.f / (1.f + __expf(-(xr + ghr)));
    const float z = 1.f / (1.f + __expf(-(xz + ghz)));
    float nv;
    {
      const float a = xn + rg * ghn;
      const float tt = __expf(-2.f * fabsf(a));
      nv = (1.f - tt) / (1.f + tt);
      nv = a < 0.f ? -nv : nv;
    }
    hown = (1.f - z) * nv + z * hown;
    // write-through h store, then ACK it (vmcnt(0)) -- flag-visible ==> data
    // committed, so the consumer's single bulk load is sufficient.
    {
      f16* hdst = HB + ((size_t)((s + 1) & 1) << 16) + ((size_t)(brow0 + b) << 10) + ugl;
      union { f16 h; unsigned short us; } cv;
      cv.h = (f16)hown;
      u32 hv = (u32)cv.us;
      asm volatile("global_store_short %0, %1, off sc0 sc1"
                   :: "v"(hdst), "v"(hv) : "memory");
    }
    if (s == NS - 1) hlast[(size_t)(brow0 + b) * NH + ugl] = hown;
    asm volatile("s_waitcnt vmcnt(0)" ::: "memory");  // own store complete at IF$
    __syncthreads();                      // sync #2: ALL threads' stores acked;
                                          // also WAR-guards red[]
    if (tid == 0) {
      u32 fv = (u32)(s + 1);
      asm volatile("global_store_dword %0, %1, off sc0 sc1"
                   :: "v"(fdst), "v"(fv) : "memory");
      // fire-and-forget; retirement folded into next step's vmcnt(0) ack
    }
  }
}

// ---------------------------------------------------------------- FC head
__global__ __launch_bounds__(64) void fc_k(const float* __restrict__ hl,
                                           const float* __restrict__ fw,
                                           const float* __restrict__ fb,
                                           float* __restrict__ out) {
  int b = blockIdx.x, t = threadIdx.x;
  float a0 = 0.f, a1 = 0.f;
  for (int k = t; k < NH; k += 64) {
    float h = hl[b * NH + k];
    a0 += h * fw[k];
    a1 += h * fw[NH + k];
  }
  #pragma unroll
  for (int off = 32; off; off >>= 1) {
    a0 += __shfl_down(a0, off);
    a1 += __shfl_down(a1, off);
  }
  if (t == 0) {
    out[b * 2 + 0] = a0 + fb[0];
    out[b * 2 + 1] = a1 + fb[1];
  }
}

// ---------------------------------------------------------------- launcher
extern "C" void kernel_launch(void* const* d_in, const int* in_sizes, int n_in,
                              void* d_out, int out_size, void* d_ws, size_t ws_size,
                              hipStream_t stream) {
  const int*   seq = (const int*)d_in[0];
  const float* emb = (const float*)d_in[1];
  const float* wih = (const float*)d_in[2];
  const float* whh = (const float*)d_in[3];
  const float* bih = (const float*)d_in[4];
  const float* bhh = (const float*)d_in[5];
  const float* fcw = (const float*)d_in[6];
  const float* fcb = (const float*)d_in[7];
  float* out = (float*)d_out;

  char* ws = (char*)d_ws;
  size_t off = 0;
  f16* X = (f16*)(ws + off);   off += (size_t)NS * NB * NE * 2;   // 33.6 MB
  f16* W16 = (f16*)(ws + off); off += (size_t)G3 * NE * 2;        // 3.1 MB
  f16* GX = (f16*)(ws + off);  off += (size_t)NS * NB * G3 * 2;   // 201 MB
  f16* HB = (f16*)(ws + off);  off += (size_t)2 * NB * NH * 2;    // 256 KB
  u32* FLG = (u32*)(ws + off); off += (size_t)4 * 64 * FSTR * 4;  // 32 KB (after HB!)
  float* HL = (float*)(ws + off); off += (size_t)NB * NH * 4;     // 256 KB
  if (ws_size < off) return;  // insufficient workspace -> fail visibly, no OOB

  // Zero h0 (parity-0 buffer) and flags every call (ws is 0xAA-poisoned).
  // HB and FLG are contiguous -> one memset.
  hipMemsetAsync(HB, 0, (size_t)2 * NB * NH * 2 + (size_t)4 * 64 * FSTR * 4, stream);

  embed_k<<<(NS * NB) / 4, 256, 0, stream>>>(seq, emb, X);
  wconv<<<(G3 * NE) / 1024, 256, 0, stream>>>(wih, W16);
  gemm_gx<<<256 * 24, 256, 0, stream>>>(X, W16, bih, GX);
  gru_rec<<<256, 256, 0, stream>>>(whh, bhh, GX, HB, FLG, HL);
  fc_k<<<NB, 64, 0, stream>>>(HL, fcw, fcb, out);
}

// Round 9
// 1959.630 us; speedup vs baseline: 1.5851x; 1.0592x over previous
//
#include <hip/hip_runtime.h>
#include <stdint.h>
#include <stddef.h>

// ---------------------------------------------------------------------------
// Discriminator: embedding [64,512] -> GRU(512->1024, 512 steps) -> FC(1024->2)
//   k1 embed_k : gather emb rows -> X fp16 [S*B, 512]   (row = s*64+b)
//   k2 wconv   : w_ih fp32 -> fp16
//   k3 gemm_gx : GX = X @ w_ih^T + b_ih  -> fp16 [S*B, 3072]  (MFMA 128x128 tile)
//   k4 gru_rec : persistent 256-WG kernel, 4 batch-groups x 64 unit-groups.
//                R8 sync (per-producer 128B-strided flags, ack'd sc0sc1 h
//                stores). THIS ROUND: w_hh B-frags moved LDS -> REGISTERS
//                (96 VGPR/lane, loop-invariant) + f32x4 red reduce. Zero
//                per-step LDS traffic except the 15KB red exchange.
//   k5 fc_k    : logits = h_last @ fc_w^T + fc_b -> d_out fp32 [64,2]
// ---------------------------------------------------------------------------

typedef _Float16 f16;
typedef _Float16 f16x4 __attribute__((ext_vector_type(4)));
typedef _Float16 f16x8 __attribute__((ext_vector_type(8)));
typedef float f32x4 __attribute__((ext_vector_type(4)));
typedef unsigned int u32;

#define NB 64      // batch
#define NS 512     // seq len
#define NE 512     // embedding dim
#define NH 1024    // hidden
#define G3 3072    // 3*NH
#define FSTR 32    // flag stride in dwords (128B lines -> parallel commits)

// ---------------------------------------------------------------- embedding
__global__ __launch_bounds__(256) void embed_k(const int* __restrict__ seq,
                                               const float* __restrict__ emb,
                                               f16* __restrict__ X) {
  int rr = blockIdx.x * 4 + (threadIdx.x >> 6);   // row = s*64 + b
  int lane = threadIdx.x & 63;
  int s = rr >> 6, b = rr & 63;
  int idx = seq[b * NS + s];
  const float* src = emb + (size_t)idx * NE + lane * 8;
  float4 v0 = *(const float4*)(src);
  float4 v1 = *(const float4*)(src + 4);
  f16x8 o;
  o[0] = (f16)v0.x; o[1] = (f16)v0.y; o[2] = (f16)v0.z; o[3] = (f16)v0.w;
  o[4] = (f16)v1.x; o[5] = (f16)v1.y; o[6] = (f16)v1.z; o[7] = (f16)v1.w;
  *(f16x8*)(&X[(size_t)rr * NE + lane * 8]) = o;
}

// ---------------------------------------------------------------- w_ih -> fp16
__global__ __launch_bounds__(256) void wconv(const float* __restrict__ w,
                                             f16* __restrict__ o) {
  int i = (blockIdx.x * 256 + threadIdx.x) * 4;
  float4 v = *(const float4*)(&w[i]);
  f16x4 t = {(f16)v.x, (f16)v.y, (f16)v.z, (f16)v.w};
  *(f16x4*)(&o[i]) = t;
}

// ---------------------------------------------------------------- gx GEMM
// C[m,g] = sum_k X[m,k] * W[g,k] + bih[g];  M=32768 N=3072 K=512
__global__ __launch_bounds__(256) void gemm_gx(const f16* __restrict__ X,
                                               const f16* __restrict__ W,
                                               const float* __restrict__ bih,
                                               f16* __restrict__ GX) {
  __shared__ f16 As[128][40];   // +8 pad: frag-read 2-way banks only
  __shared__ f16 Bs[128][40];
  int tm = blockIdx.x & 255, tn = blockIdx.x >> 8;   // 256 x 24
  int m0 = tm * 128, n0 = tn * 128;
  int tid = threadIdx.x, lane = tid & 63, w = tid >> 6;
  int wm = w & 1, wn = w >> 1;
  f32x4 acc[4][4] = {};
  for (int k0 = 0; k0 < 512; k0 += 32) {
    __syncthreads();
    #pragma unroll
    for (int i = 0; i < 2; i++) {
      int c = tid + i * 256;          // 512 chunks of 16B per operand
      int r = c >> 2, seg = c & 3;
      *(f16x8*)(&As[r][seg * 8]) = *(const f16x8*)(&X[(size_t)(m0 + r) * 512 + k0 + seg * 8]);
      *(f16x8*)(&Bs[r][seg * 8]) = *(const f16x8*)(&W[(size_t)(n0 + r) * 512 + k0 + seg * 8]);
    }
    __syncthreads();
    f16x8 af[4], bf[4];
    int rA = lane & 15, kA = (lane >> 4) * 8;
    #pragma unroll
    for (int i = 0; i < 4; i++) af[i] = *(const f16x8*)(&As[wm * 64 + i * 16 + rA][kA]);
    #pragma unroll
    for (int j = 0; j < 4; j++) bf[j] = *(const f16x8*)(&Bs[wn * 64 + j * 16 + rA][kA]);
    #pragma unroll
    for (int i = 0; i < 4; i++)
      #pragma unroll
      for (int j = 0; j < 4; j++)
        acc[i][j] = __builtin_amdgcn_mfma_f32_16x16x32_f16(af[i], bf[j], acc[i][j], 0, 0, 0);
  }
  int col = lane & 15, rq = lane >> 4;
  #pragma unroll
  for (int j = 0; j < 4; j++) {
    int g = n0 + wn * 64 + j * 16 + col;
    float bias = bih[g];
    #pragma unroll
    for (int i = 0; i < 4; i++) {
      int mbase = m0 + wm * 64 + i * 16 + rq * 4;
      #pragma unroll
      for (int q = 0; q < 4; q++)
        GX[(size_t)(mbase + q) * G3 + g] = (f16)(acc[i][j][q] + bias);
    }
  }
}

// ---------------------------------------------------------------- GRU recurrence
// HB: f16 [2][64][1024], buffer p holds h^(s) for s == p (mod 2).
// FLG[bg][ug*FSTR]: flag = steps completed by WG (bg,ug), stored (plain sc0sc1
// dword, no RMW) AFTER the WG's h stores are acked at the coherence point
// (per-thread vmcnt(0)) + __syncthreads. flag>=s+1 ==> h^(s+1) readable.
// Consumer: each wave polls all 64 flags (one per lane) until __all(>= s),
// then ONE bulk load suffices. WAR safety: overwriting h^(s-1) happens only
// after all flags >= s, i.e. every same-bg WG bulk-READ h^(s-1) already.
// w_hh B-frags are REGISTER-RESIDENT (bfr[3][8], 96 VGPR/lane, loop-invariant)
// -> no per-step LDS reads; only the 15KB red[] inter-wave reduce remains.
__global__ __launch_bounds__(256, 1) void gru_rec(const float* __restrict__ whh,
                                                  const float* __restrict__ bhh,
                                                  const f16* __restrict__ GX,
                                                  f16* __restrict__ HB,       // [2][64][1024]
                                                  u32* __restrict__ FLG,      // [4][64*FSTR]
                                                  float* __restrict__ hlast) { // [64][1024]
  // red[wv][n][col r][row b (padded 16->20, keeps 16B align + bank spread)]
  __shared__ float red[4][3][16][20];
  const int tid = threadIdx.x, lane = tid & 63, wv = tid >> 6;
  const int bg = blockIdx.x >> 6, ug = blockIdx.x & 63;
  const int brow0 = bg * 16;
  const int q = lane >> 4, r = lane & 15;

  // ---- loop-invariant w_hh B-fragments -> registers (96 VGPRs/lane).
  // lane (q,r) elem j of bfr[n][kk] = W[n*1024 + ug*16 + r][wv*256 + kk*32 + q*8 + j]
  // (identical operand values to R8's wl[n*16+r][kof] reads -> correctness
  //  preserved by construction)
  f16x8 bfr[3][8];
  #pragma unroll
  for (int n = 0; n < 3; n++)
    #pragma unroll
    for (int kk = 0; kk < 8; kk++) {
      const float* p = whh + (size_t)(n * NH + ug * 16 + r) * NH + wv * 256 + kk * 32 + q * 8;
      float4 v0 = *(const float4*)p;
      float4 v1 = *(const float4*)(p + 4);
      f16x8 t;
      t[0] = (f16)v0.x; t[1] = (f16)v0.y; t[2] = (f16)v0.z; t[3] = (f16)v0.w;
      t[4] = (f16)v1.x; t[5] = (f16)v1.y; t[6] = (f16)v1.z; t[7] = (f16)v1.w;
      bfr[n][kk] = t;
    }

  const int b = tid >> 4, u = tid & 15;
  const int ugl = ug * 16 + u;
  const float bh_r = bhh[ugl], bh_z = bhh[NH + ugl], bh_n = bhh[2 * NH + ugl];
  float hown = 0.f;
  const u32* fpoll = FLG + bg * (64 * FSTR) + lane * FSTR;  // per-lane flag
  u32* fdst = FLG + bg * (64 * FSTR) + ug * FSTR;           // own flag

  #pragma unroll 1
  for (int s = 0; s < NS; s++) {
    // prefetch gx_t (plain cached loads; latency hides under the flag poll)
    const f16* gxp = GX + ((size_t)s * NB + brow0 + b) * G3 + ugl;
    f16 gr16 = gxp[0], gz16 = gxp[NH], gn16 = gxp[2 * NH];

    // ---- wave-autonomous flag poll: lane i watches producer i of this bg.
    {
      const u32 target = (u32)s;
      for (;;) {
        u32 fv;
        asm volatile("global_load_dword %0, %1, off sc0 sc1\n\t"
                     "s_waitcnt vmcnt(0)"
                     : "=v"(fv) : "v"(fpoll) : "memory");
        if (__all(fv >= target)) break;
        __builtin_amdgcn_s_sleep(1);
      }
    }

    // ---- single bulk load of h^(s) (fp16, lands directly as MFMA A-frags).
    // wave wv covers k in [wv*256, wv*256+256); lane (q,r): row brow0+r,
    // k = wv*256 + kk*32 + q*8 + {0..7}, kk=0..7.  8 x dwordx4 = 32KB/WG.
    f16x8 af[8];
    {
      const f16* hrow = HB + ((size_t)(s & 1) << 16)
                           + ((size_t)(brow0 + r) << 10) + wv * 256 + q * 8;
      asm volatile(
        "global_load_dwordx4 %0, %[p], off sc0 sc1\n\t"
        "global_load_dwordx4 %1, %[p], off offset:64 sc0 sc1\n\t"
        "global_load_dwordx4 %2, %[p], off offset:128 sc0 sc1\n\t"
        "global_load_dwordx4 %3, %[p], off offset:192 sc0 sc1\n\t"
        "global_load_dwordx4 %4, %[p], off offset:256 sc0 sc1\n\t"
        "global_load_dwordx4 %5, %[p], off offset:320 sc0 sc1\n\t"
        "global_load_dwordx4 %6, %[p], off offset:384 sc0 sc1\n\t"
        "global_load_dwordx4 %7, %[p], off offset:448 sc0 sc1\n\t"
        "s_waitcnt vmcnt(0)"
        : "=&v"(af[0]), "=&v"(af[1]), "=&v"(af[2]), "=&v"(af[3]),
          "=&v"(af[4]), "=&v"(af[5]), "=&v"(af[6]), "=&v"(af[7])
        : [p] "v"(hrow)
        : "memory");
      __builtin_amdgcn_sched_barrier(0);  // rule #18: keep MFMA after the waitcnt
    }
    f32x4 ac0 = {}, ac1 = {}, ac2 = {};
    #pragma unroll
    for (int kk = 0; kk < 8; kk++) {
      ac0 = __builtin_amdgcn_mfma_f32_16x16x32_f16(af[kk], bfr[0][kk], ac0, 0, 0, 0);
      ac1 = __builtin_amdgcn_mfma_f32_16x16x32_f16(af[kk], bfr[1][kk], ac1, 0, 0, 0);
      ac2 = __builtin_amdgcn_mfma_f32_16x16x32_f16(af[kk], bfr[2][kk], ac2, 0, 0, 0);
    }
    // acc element q2 = C[row q*4+q2][col r] -> red[wv][n][r][q*4+q2] (f32x4)
    *(f32x4*)(&red[wv][0][r][q * 4]) = ac0;
    *(f32x4*)(&red[wv][1][r][q * 4]) = ac1;
    *(f32x4*)(&red[wv][2][r][q * 4]) = ac2;
    __syncthreads();                      // sync #1: red ready
    float ghr = bh_r, ghz = bh_z, ghn = bh_n;
    #pragma unroll
    for (int w2 = 0; w2 < 4; w2++) {
      ghr += red[w2][0][u][b];
      ghz += red[w2][1][u][b];
      ghn += red[w2][2][u][b];
    }
    const float xr = (float)gr16, xz = (float)gz16, xn = (float)gn16;
    const float rg = 1.f / (1.f + __expf(-(xr + ghr)));
    const float z = 1.f / (1.f + __expf(-(xz + ghz)));
    float nv;
    {
      const float a = xn + rg * ghn;
      const float tt = __expf(-2.f * fabsf(a));
      nv = (1.f - tt) / (1.f + tt);
      nv = a < 0.f ? -nv : nv;
    }
    hown = (1.f - z) * nv + z * hown;
    // write-through h store, then ACK it (vmcnt(0)) -- flag-visible ==> data
    // committed, so the consumer's single bulk load is sufficient.
    {
      f16* hdst = HB + ((size_t)((s + 1) & 1) << 16) + ((size_t)(brow0 + b) << 10) + ugl;
      union { f16 h; unsigned short us; } cv;
      cv.h = (f16)hown;
      u32 hv = (u32)cv.us;
      asm volatile("global_store_short %0, %1, off sc0 sc1"
                   :: "v"(hdst), "v"(hv) : "memory");
    }
    if (s == NS - 1) hlast[(size_t)(brow0 + b) * NH + ugl] = hown;
    asm volatile("s_waitcnt vmcnt(0)" ::: "memory");  // own store complete at IF$
    __syncthreads();                      // sync #2: ALL threads' stores acked;
                                          // also WAR-guards red[]
    if (tid == 0) {
      u32 fv = (u32)(s + 1);
      asm volatile("global_store_dword %0, %1, off sc0 sc1"
                   :: "v"(fdst), "v"(fv) : "memory");
      // fire-and-forget; retirement folded into next step's vmcnt(0) ack
    }
  }
}

// ---------------------------------------------------------------- FC head
__global__ __launch_bounds__(64) void fc_k(const float* __restrict__ hl,
                                           const float* __restrict__ fw,
                                           const float* __restrict__ fb,
                                           float* __restrict__ out) {
  int b = blockIdx.x, t = threadIdx.x;
  float a0 = 0.f, a1 = 0.f;
  for (int k = t; k < NH; k += 64) {
    float h = hl[b * NH + k];
    a0 += h * fw[k];
    a1 += h * fw[NH + k];
  }
  #pragma unroll
  for (int off = 32; off; off >>= 1) {
    a0 += __shfl_down(a0, off);
    a1 += __shfl_down(a1, off);
  }
  if (t == 0) {
    out[b * 2 + 0] = a0 + fb[0];
    out[b * 2 + 1] = a1 + fb[1];
  }
}

// ---------------------------------------------------------------- launcher
extern "C" void kernel_launch(void* const* d_in, const int* in_sizes, int n_in,
                              void* d_out, int out_size, void* d_ws, size_t ws_size,
                              hipStream_t stream) {
  const int*   seq = (const int*)d_in[0];
  const float* emb = (const float*)d_in[1];
  const float* wih = (const float*)d_in[2];
  const float* whh = (const float*)d_in[3];
  const float* bih = (const float*)d_in[4];
  const float* bhh = (const float*)d_in[5];
  const float* fcw = (const float*)d_in[6];
  const float* fcb = (const float*)d_in[7];
  float* out = (float*)d_out;

  char* ws = (char*)d_ws;
  size_t off = 0;
  f16* X = (f16*)(ws + off);   off += (size_t)NS * NB * NE * 2;   // 33.6 MB
  f16* W16 = (f16*)(ws + off); off += (size_t)G3 * NE * 2;        // 3.1 MB
  f16* GX = (f16*)(ws + off);  off += (size_t)NS * NB * G3 * 2;   // 201 MB
  f16* HB = (f16*)(ws + off);  off += (size_t)2 * NB * NH * 2;    // 256 KB
  u32* FLG = (u32*)(ws + off); off += (size_t)4 * 64 * FSTR * 4;  // 32 KB (after HB!)
  float* HL = (float*)(ws + off); off += (size_t)NB * NH * 4;     // 256 KB
  if (ws_size < off) return;  // insufficient workspace -> fail visibly, no OOB

  // Zero h0 (parity-0 buffer) and flags every call (ws is 0xAA-poisoned).
  // HB and FLG are contiguous -> one memset.
  hipMemsetAsync(HB, 0, (size_t)2 * NB * NH * 2 + (size_t)4 * 64 * FSTR * 4, stream);

  embed_k<<<(NS * NB) / 4, 256, 0, stream>>>(seq, emb, X);
  wconv<<<(G3 * NE) / 1024, 256, 0, stream>>>(wih, W16);
  gemm_gx<<<256 * 24, 256, 0, stream>>>(X, W16, bih, GX);
  gru_rec<<<256, 256, 0, stream>>>(whh, bhh, GX, HB, FLG, HL);
  fc_k<<<NB, 64, 0, stream>>>(HL, fcw, fcb, out);
}